// Round 4
// baseline (8210.542 us; speedup 1.0000x reference)
//
#include <hip/hip_runtime.h>

typedef __attribute__((ext_vector_type(8))) short bf16frag;
typedef __attribute__((ext_vector_type(4))) float f32x4;
typedef __attribute__((ext_vector_type(4))) unsigned int u32x4;

constexpr int B = 128, S = 1024, DI = 256, DH = 512, DO = 256;
constexpr size_t OUT_MAIN = (size_t)B * S * DO;     // elements
constexpr size_t SLOT_U32 = (size_t)B * DH;         // tagged u32 per ring slot
constexpr size_t SLOT_BYTES = SLOT_U32 * 4;         // 262144
constexpr size_t FLAGS_BYTES = 8 * 64 * 4;          // per cluster: 32 hints + 16 sentL + pad
// LDS layout (ushort units)
constexpr int WH_OFF = 0;        // 32 x 512
constexpr int WX_OFF = 16384;    // 32 x 256
constexpr int WHO_OFF = 24576;   // 16 x 512
constexpr int RING_OFF = 32768;  // 4 slots x 16 x 512 ushorts (64 KB), XOR-swizzled
constexpr int LDS_BYTES = 131072 + 256;             // + lf/w2p flag words

__device__ __forceinline__ unsigned short f2bf(float f) {
  unsigned int u = __float_as_uint(f);
  u += 0x7fffu + ((u >> 16) & 1u);          // RNE
  return (unsigned short)(u >> 16);
}
__device__ __forceinline__ float bf2f(unsigned short h) {
  return __uint_as_float(((unsigned int)h) << 16);
}
__device__ __forceinline__ float fast_tanh(float x) {
  float e = __expf(2.0f * x);               // inf-safe: e=inf -> 1 ; e=0 -> -1
  return 1.0f - 2.0f * __builtin_amdgcn_rcpf(e + 1.0f);
}
__device__ __forceinline__ bf16frag cvt8(float4 a, float4 b) {
  bf16frag r;
  r[0]=(short)f2bf(a.x); r[1]=(short)f2bf(a.y); r[2]=(short)f2bf(a.z); r[3]=(short)f2bf(a.w);
  r[4]=(short)f2bf(b.x); r[5]=(short)f2bf(b.y); r[6]=(short)f2bf(b.z); r[7]=(short)f2bf(b.w);
  return r;
}
__device__ __forceinline__ bf16frag load8(const void* base, size_t off, bool fp32m) {
  if (fp32m) {
    const float4* p = reinterpret_cast<const float4*>((const float*)base + off);
    return cvt8(p[0], p[1]);
  }
  return *reinterpret_cast<const bf16frag*>((const unsigned short*)base + off);
}

// plain MALL-path store (no atomic RMW, no release — tags carry validity)
__device__ __forceinline__ void sc_store(int* p, int v) {
  asm volatile("global_store_dword %0, %1, off sc0 sc1" :: "v"(p), "v"(v) : "memory");
}

// Hint poll: lane<32 -> producer hints >= vthr (own wave0 hint excluded via skip);
// lanes 32..47 -> loader progress sentL >= lthr (ring-reuse slack). One coalesced
// 192B poll round. Bounded: terminate instead of hang.
__device__ __forceinline__ void poll48(const int* cflag, int vthr, int lthr, int skip) {
  const int lane = threadIdx.x & 63;
  const int* addr = cflag + (lane < 48 ? lane : 0);
  int thr = (lane < 32 || lane >= 48) ? vthr : lthr;
  if (lane == skip) thr = (int)0x80000000;     // own hint: tags cover the race
  int g = 0;
  while (true) {
    int x;
    asm volatile("global_load_dword %0, %1, off sc0 sc1\n\t"
                 "s_waitcnt vmcnt(0)" : "=v"(x) : "v"(addr) : "memory");
    if (__all(x >= thr)) break;
    if (++g > (1 << 24)) break;
    __builtin_amdgcn_s_sleep(1);
  }
}

__global__ void __launch_bounds__(192, 1)
rnn_persistent(const void* __restrict__ xv,
               const void* __restrict__ Wi2hv,
               const void* __restrict__ biv,
               const void* __restrict__ Whov,
               const void* __restrict__ bov,
               void* __restrict__ outv,
               unsigned int* __restrict__ hbuf,   // tagged u32 ring
               int* __restrict__ flags,
               int nb) {                           // global ring depth (2..4)
  extern __shared__ unsigned short lds[];
  int* lf  = (int*)((char*)lds + 131072);   // wave0 publish step
  int* w2p = lf + 1;                        // wave2 progress
  const int tid = threadIdx.x;
  const int lane = tid & 63;
  const int wave = tid >> 6;     // 0: loader+rec tile0; 1: rec tile1; 2: out GEMM
  const int blk = blockIdx.x;
  const int c   = blk & 7;       // cluster (batch slice)
  const int mem = blk >> 3;      // member 0..15 (hidden/out slice)
  const int b0  = c * 16;
  const int n_base = mem * 32;
  const int o_base = mem * 16;

  // ---- dtype detection (fp32 vs bf16 inputs) ----
  bool fp32m;
  {
    const unsigned short* xu = (const unsigned short*)xv;
    int c0 = 0;
    for (int i = lane; i < 4096; i += 64)
      c0 += (((xu[i] >> 7) & 0xFF) >= 0xC0);
    #pragma unroll
    for (int s = 32; s; s >>= 1) c0 += __shfl_xor(c0, s, 64);
    fp32m = (c0 > 100);
  }

  // ---- stage weight slices into LDS (bf16), 16B-block XOR swizzle ----
  for (int i = tid; i < 32 * 64; i += 192) {              // Wh: 32 x 512
    int r = i >> 6, bk = i & 63;
    bf16frag v = load8(Wi2hv, (size_t)(n_base + r) * 768 + 256 + bk * 8, fp32m);
    *reinterpret_cast<bf16frag*>(lds + WH_OFF + r * 512 + ((bk ^ (r & 7)) * 8)) = v;
  }
  for (int i = tid; i < 32 * 32; i += 192) {              // Wx: 32 x 256
    int r = i >> 5, bk = i & 31;
    bf16frag v = load8(Wi2hv, (size_t)(n_base + r) * 768 + bk * 8, fp32m);
    *reinterpret_cast<bf16frag*>(lds + WX_OFF + r * 256 + ((bk ^ (r & 7)) * 8)) = v;
  }
  for (int i = tid; i < 16 * 64; i += 192) {              // Who: 16 x 512
    int r = i >> 6, bk = i & 63;
    bf16frag v = load8(Whov, (size_t)(o_base + r) * 512 + bk * 8, fp32m);
    *reinterpret_cast<bf16frag*>(lds + WHO_OFF + r * 512 + ((bk ^ (r & 7)) * 8)) = v;
  }
  if (tid == 0) { *lf = 0; *w2p = 0; }
  __syncthreads();

  int* cflag = flags + c * 64;   // [0..31] hints (2*mem+w), [32..47] sentL (mem)
  const int q  = lane >> 4;
  const int ln = lane & 15;
  float* outf = (float*)outv;
  unsigned short* outh = (unsigned short*)outv;
  char* ringb = (char*)lds + RING_OFF * 2;

  if (wave < 2) {
    const int nlB = wave * 16 + ln;
    const int n_g = n_base + nlB;
    const float bias = fp32m ? ((const float*)biv)[n_g]
                             : bf2f(((const unsigned short*)biv)[n_g]);
    const int swz = nlB & 7;
    const size_t xrow = (size_t)(b0 + ln) * (S * DI) + q * 8;
    // loader's per-lane tagged-load base: row b0+ln, dim q*8 (+kk*32)
    const unsigned int* hs_base = hbuf + (size_t)(b0 + ln) * DH + q * 8;

    bf16frag xf[8];
    #pragma unroll
    for (int cc = 0; cc < 8; ++cc)
      xf[cc] = load8(xv, xrow + cc * 32, fp32m);

    int ps = 0;            // v % nb (store slot)
    int pps = 0;           // (v-1) % nb (load slot), valid for v>0
    for (int v = 0; v < S; ++v) {
      f32x4 acc = {bias, bias, bias, bias};
      #pragma unroll
      for (int cc = 0; cc < 8; ++cc) {            // x-part (overlaps the wait)
        bf16frag wf = *reinterpret_cast<const bf16frag*>(
            lds + WX_OFF + nlB * 256 + (((cc * 4 + q) ^ swz) * 8));
        acc = __builtin_amdgcn_mfma_f32_16x16x32_bf16(xf[cc], wf, acc, 0, 0, 0);
      }
      if (v + 1 < S) {                            // prefetch next x; drained by poll
        #pragma unroll
        for (int cc = 0; cc < 8; ++cc)
          xf[cc] = load8(xv, xrow + (size_t)(v + 1) * DI + cc * 32, fp32m);
      }
      if (v > 0) {
        if (wave == 0) {
          // -- loader: hints say stores fired; sentL guards slot reuse --
          poll48(cflag, v, v - (nb - 1), 2 * mem);
          const unsigned int thr = (unsigned int)v << 16;
          const unsigned int* hs = hs_base + (size_t)pps * SLOT_U32;
          u32x4 hv[32];
          int gg = 0;
          while (true) {                          // one-RTT tagged pull + validate
            #pragma unroll
            for (int i = 0; i < 32; ++i) {
              const unsigned int* p = hs + (i >> 1) * 32 + (i & 1) * 4;
              asm volatile("global_load_dwordx4 %0, %1, off sc0 sc1"
                           : "=v"(hv[i]) : "v"(p) : "memory");
            }
            asm volatile("s_waitcnt vmcnt(0)" ::: "memory");
            __builtin_amdgcn_sched_barrier(0);
            bool ok = true;
            #pragma unroll
            for (int i = 0; i < 32; ++i) {
              #pragma unroll
              for (int e = 0; e < 4; ++e) ok &= (hv[i][e] >= thr);
            }
            if (__all(ok)) break;
            if (++gg > (1 << 16)) break;          // loud failure over hang
          }
          if (lane == 0) sc_store(cflag + 32 + mem, v);   // slot consumed
          // LDS ring reuse: wave2 must be done with slot (v-1)&3's old step
          int g2 = 0;
          while (__hip_atomic_load(w2p, __ATOMIC_ACQUIRE, __HIP_MEMORY_SCOPE_WORKGROUP)
                     < v - 4 && ++g2 < (1 << 24))
            __builtin_amdgcn_s_sleep(1);
          // strip tags -> packed A-frags; publish to LDS ring for wave1/wave2
          char* rb = ringb + ((v - 1) & 3) * 16384 + ln * 1024;
          u32x4 pa[16];
          #pragma unroll
          for (int kk = 0; kk < 16; ++kk) {
            u32x4 t0 = hv[2 * kk], t1 = hv[2 * kk + 1], pk;
            pk[0] = (t0[0] & 0xFFFFu) | (t0[1] << 16);
            pk[1] = (t0[2] & 0xFFFFu) | (t0[3] << 16);
            pk[2] = (t1[0] & 0xFFFFu) | (t1[1] << 16);
            pk[3] = (t1[2] & 0xFFFFu) | (t1[3] << 16);
            pa[kk] = pk;
            int u = kk * 4 + q;
            *reinterpret_cast<u32x4*>(rb + ((u ^ (ln & 7)) * 16)) = pk;
          }
          __hip_atomic_store(lf, v, __ATOMIC_RELEASE, __HIP_MEMORY_SCOPE_WORKGROUP);
          #pragma unroll
          for (int kk = 0; kk < 16; ++kk) {
            union { u32x4 u; bf16frag f; } cv; cv.u = pa[kk];
            bf16frag wf = *reinterpret_cast<const bf16frag*>(
                lds + WH_OFF + nlB * 512 + (((kk * 4 + q) ^ swz) * 8));
            acc = __builtin_amdgcn_mfma_f32_16x16x32_bf16(cv.f, wf, acc, 0, 0, 0);
          }
        } else {
          // -- wave1: consume h from LDS ring --
          int g2 = 0;
          while (__hip_atomic_load(lf, __ATOMIC_ACQUIRE, __HIP_MEMORY_SCOPE_WORKGROUP)
                     < v && ++g2 < (1 << 24)) {}
          char* rb = ringb + ((v - 1) & 3) * 16384 + ln * 1024;
          #pragma unroll
          for (int kk = 0; kk < 16; ++kk) {
            int u = kk * 4 + q;
            u32x4 pk = *reinterpret_cast<const u32x4*>(rb + ((u ^ (ln & 7)) * 16));
            union { u32x4 u_; bf16frag f; } cv; cv.u_ = pk;
            bf16frag wf = *reinterpret_cast<const bf16frag*>(
                lds + WH_OFF + nlB * 512 + (((kk * 4 + q) ^ swz) * 8));
            acc = __builtin_amdgcn_mfma_f32_16x16x32_bf16(cv.f, wf, acc, 0, 0, 0);
          }
        }
      }
      // tanh -> tagged store (tag = v+1 rides with each bf16; no release needed)
      const unsigned int tag = (unsigned int)(v + 1) << 16;
      unsigned int* hd = hbuf + (size_t)ps * SLOT_U32;
      #pragma unroll
      for (int r = 0; r < 4; ++r) {
        float hvf = fast_tanh(acc[r]);
        unsigned short hu = f2bf(hvf);
        unsigned int tw = tag | (unsigned int)hu;
        unsigned int* p = hd + (size_t)(b0 + q * 4 + r) * DH + n_g;
        asm volatile("global_store_dword %0, %1, off sc0 sc1"
                     :: "v"(p), "v"(tw) : "memory");
        if (v == S - 1) {
          size_t hidx = OUT_MAIN + (size_t)(b0 + q * 4 + r) * DH + n_g;
          if (fp32m) outf[hidx] = hvf; else outh[hidx] = hu;   // h_last
        }
      }
      if (lane == 0) sc_store(cflag + 2 * mem + wave, v + 1);  // hint (no ack wait)
      pps = ps;
      ps = (ps + 1 == nb) ? 0 : ps + 1;
    }
    // epilogue: wave0 publishes h_{S-1} to the LDS ring so wave2 can finish
    if (wave == 0) {
      poll48(cflag, S, S - (nb - 1), 2 * mem);
      const unsigned int thr = (unsigned int)S << 16;
      const unsigned int* hs = hs_base + (size_t)pps * SLOT_U32;
      u32x4 hv[32];
      int gg = 0;
      while (true) {
        #pragma unroll
        for (int i = 0; i < 32; ++i) {
          const unsigned int* p = hs + (i >> 1) * 32 + (i & 1) * 4;
          asm volatile("global_load_dwordx4 %0, %1, off sc0 sc1"
                       : "=v"(hv[i]) : "v"(p) : "memory");
        }
        asm volatile("s_waitcnt vmcnt(0)" ::: "memory");
        __builtin_amdgcn_sched_barrier(0);
        bool ok = true;
        #pragma unroll
        for (int i = 0; i < 32; ++i) {
          #pragma unroll
          for (int e = 0; e < 4; ++e) ok &= (hv[i][e] >= thr);
        }
        if (__all(ok)) break;
        if (++gg > (1 << 16)) break;
      }
      int g2 = 0;
      while (__hip_atomic_load(w2p, __ATOMIC_ACQUIRE, __HIP_MEMORY_SCOPE_WORKGROUP)
                 < S - 4 && ++g2 < (1 << 24))
        __builtin_amdgcn_s_sleep(1);
      char* rb = ringb + ((S - 1) & 3) * 16384 + ln * 1024;
      #pragma unroll
      for (int kk = 0; kk < 16; ++kk) {
        u32x4 t0 = hv[2 * kk], t1 = hv[2 * kk + 1], pk;
        pk[0] = (t0[0] & 0xFFFFu) | (t0[1] << 16);
        pk[1] = (t0[2] & 0xFFFFu) | (t0[3] << 16);
        pk[2] = (t1[0] & 0xFFFFu) | (t1[1] << 16);
        pk[3] = (t1[2] & 0xFFFFu) | (t1[3] << 16);
        int u = kk * 4 + q;
        *reinterpret_cast<u32x4*>(rb + ((u ^ (ln & 7)) * 16)) = pk;
      }
      __hip_atomic_store(lf, S, __ATOMIC_RELEASE, __HIP_MEMORY_SCOPE_WORKGROUP);
    }
  } else {
    // wave2: out_u = h_u @ Who^T + b, fed entirely from the LDS ring
    const int o_g = o_base + ln;
    const float bias = fp32m ? ((const float*)bov)[o_g]
                             : bf2f(((const unsigned short*)bov)[o_g]);
    const int swzW = ln & 7;
    for (int u = 0; u < S; ++u) {
      int g2 = 0;
      while (__hip_atomic_load(lf, __ATOMIC_ACQUIRE, __HIP_MEMORY_SCOPE_WORKGROUP)
                 < u + 1 && ++g2 < (1 << 24))
        __builtin_amdgcn_s_sleep(1);
      char* rb = ringb + (u & 3) * 16384 + ln * 1024;
      f32x4 acc = {bias, bias, bias, bias};
      f32x4 acc2 = {0.f, 0.f, 0.f, 0.f};
      #pragma unroll
      for (int kk = 0; kk < 16; ++kk) {
        int uu = kk * 4 + q;
        u32x4 pk = *reinterpret_cast<const u32x4*>(rb + ((uu ^ (ln & 7)) * 16));
        union { u32x4 a; bf16frag f; } cv; cv.a = pk;
        bf16frag wf = *reinterpret_cast<const bf16frag*>(
            lds + WHO_OFF + ln * 512 + (((kk * 4 + q) ^ swzW) * 8));
        if (kk & 1) acc2 = __builtin_amdgcn_mfma_f32_16x16x32_bf16(cv.f, wf, acc2, 0, 0, 0);
        else        acc  = __builtin_amdgcn_mfma_f32_16x16x32_bf16(cv.f, wf, acc,  0, 0, 0);
      }
      acc += acc2;
      #pragma unroll
      for (int r = 0; r < 4; ++r) {
        size_t oidx = ((size_t)(b0 + q * 4 + r) * S + u) * DO + o_g;
        if (fp32m) outf[oidx] = acc[r]; else outh[oidx] = f2bf(acc[r]);
      }
      __hip_atomic_store(w2p, u + 1, __ATOMIC_RELEASE, __HIP_MEMORY_SCOPE_WORKGROUP);
    }
  }
}

extern "C" void kernel_launch(void* const* d_in, const int* in_sizes, int n_in,
                              void* d_out, int out_size, void* d_ws, size_t ws_size,
                              hipStream_t stream) {
  const void* x    = d_in[0];
  const void* Wi2h = d_in[1];
  const void* bi   = d_in[2];
  const void* Who  = d_in[3];
  const void* bo   = d_in[4];
  void* out = d_out;

  // deepest tagged ring the workspace allows: 4 (1MB) -> 3 -> 2
  int nb = 4;
  while ((size_t)nb * SLOT_BYTES + FLAGS_BYTES > ws_size && nb > 2) nb--;
  if ((size_t)nb * SLOT_BYTES + FLAGS_BYTES > ws_size) return;  // loud failure

  unsigned int* hbuf = (unsigned int*)d_ws;
  int* flags = (int*)((char*)d_ws + (size_t)nb * SLOT_BYTES);

  // tags must start stale across graph replays: zero the whole tagged ring
  hipMemsetAsync(d_ws, 0, (size_t)nb * SLOT_BYTES + FLAGS_BYTES, stream);

  static int attr_done = 0;
  if (!attr_done) {
    hipFuncSetAttribute((const void*)rnn_persistent,
                        hipFuncAttributeMaxDynamicSharedMemorySize, LDS_BYTES);
    attr_done = 1;
  }

  void* args[] = { (void*)&x, (void*)&Wi2h, (void*)&bi, (void*)&Who, (void*)&bo,
                   (void*)&out, (void*)&hbuf, (void*)&flags, (void*)&nb };
  hipError_t e = hipLaunchCooperativeKernel((void*)rnn_persistent, dim3(128), dim3(192),
                                            args, LDS_BYTES, stream);
  if (e != hipSuccess) {
    rnn_persistent<<<dim3(128), dim3(192), LDS_BYTES, stream>>>(
        x, Wi2h, bi, Who, bo, out, hbuf, flags, nb);
  }
}